// Round 7
// baseline (1099.965 us; speedup 1.0000x reference)
//
#include <hip/hip_runtime.h>

// ---------------------------------------------------------------------------
// FCOS head on MI355X: bf16 MFMA implicit-GEMM 3x3 convs.
//   activations: padded NHWC bf16, [B][H+2][W+2][256], zero borders
//   stem weights: [s][tap][co][ci] bf16 (B^T, row-contiguous in ci)
//   pred weights: [tap][96][ci] bf16 (rows 0..79 cls, 80..83 box, 84 ctr, pad)
//
// R2: XOR chunk-swizzled LDS -> bank conflicts 5.66e7 -> 0 (verified).
// R3: vectorized epilogue via wave-private LDS transpose; level-fused grids.
// R5: tap-row A staging + exec-uniform tail slot w/ per-lane global clamp
//     (global_load_lds must be issued exec-uniformly — R4 crash).
//     Stem = 128x128 tile, 256 thr, 36KB LDS, 4 blk/CU: 192 us, MfmaUtil 46.
// R6: BN=256 variant regressed 2x (L2 thrash). Reverted; kept launch fusion.
// R7/R8: depth-1 prefetch w/ __syncthreads at 68KB LDS REGRESSED (286us):
//     __syncthreads drains the prefetch; 2 blk/CU kills TLP. Reverted.
// R9: 512-thr + __launch_bounds__(512,6) CATASTROPHIC (1531us): forced
//     VGPR<=85 -> acc spill (WRITE 86MB->4GB). >16 waves/CU unreachable.
// R10: B-dbuf + counted vmcnt(4) + raw barriers at 52KB: 202us, MfmaUtil
//     45.7 at only 12 waves/CU (occ 20.3). Per-wave eff +20% (12 waves
//     "should" give ~38%) but 3 blk/CU occupancy loss cancelled it exactly.
//     Lesson: pipeline gain is real; pay for it WITHOUT LDS.
// R13: T14 reg-staged B at R5's 36KB (4 blk/CU, 16 waves/CU): issue 4x
//     global_load_dwordx4 B(n+1)->VGPRs at compute-n start (latency hides
//     under MFMA), raw s_barrier (trailing), ds_write_b128 into the single
//     B buffer, __syncthreads (leading drains only ds_writes + A 1/3 steps).
//     Same bytes to same LDS addrs as gl_lds -> layout unchanged. VGPR ~100.
//     Predict MfmaUtil ~57%, stem ~155us, LDS 36864, WRITE 86MB.
// ---------------------------------------------------------------------------

typedef __bf16 bf16;
typedef __attribute__((ext_vector_type(8))) __bf16 bf16x8;
typedef __attribute__((ext_vector_type(4))) float f32x4;

typedef unsigned int uint32_as1 __attribute__((address_space(1)));
typedef unsigned int uint32_as3 __attribute__((address_space(3)));

__device__ __forceinline__ void gl_lds16(const bf16* g, bf16* l) {
    __builtin_amdgcn_global_load_lds(
        (const uint32_as1*)(unsigned long long)g,
        (uint32_as3*)(unsigned int)(unsigned long long)l,
        16, 0, 0);
}

struct StemTab {
    const bf16* inC[3]; const bf16* inB[3];
    bf16* outC[3]; bf16* outB[3];
    int H[3]; int lw[3]; int lhw[3];
    int xend0, xend1;
};
struct PredTab {
    const bf16* inC[3]; const bf16* inB[3];
    int H[3]; int lw[3]; int lhw[3]; int offl[3];
    int xend0, xend1;
};
struct CastTab {
    const float* in[3]; bf16* out[3];
    int H[3]; int lw[3];
    int xend0, xend1;
};
struct BZTab {
    bf16* base[3]; int H[3]; size_t bufE[3]; int ppi[3];
    int xend0, xend1;
};

// ---------------------------------------------------------------------------
// Stem conv (R13): 128x128 tile, 4 waves (2x2 of 64x64), dual-path via z,
// fused levels. K-loop: dy(3) x cq(4) x dx(3); A staged per (dy,cq) via
// global_load_lds (single-buffered); B reg-staged one step ahead
// (global->VGPR during compute, VGPR->LDS between barriers).
// ---------------------------------------------------------------------------
__global__ __launch_bounds__(256) void stem_conv_kernel(
    StemTab tab, const bf16* __restrict__ Wc, const bf16* __restrict__ Wb,
    const float* __restrict__ bc, const float* __restrict__ bb)
{
    const int bx = blockIdx.x;
    const int l  = (bx >= tab.xend0) + (bx >= tab.xend1);
    const int start = (l == 0) ? 0 : (l == 1 ? tab.xend0 : tab.xend1);
    const int local = bx - start;
    const int H = tab.H[l], lw = tab.lw[l], lhw = tab.lhw[l];

    const bf16* A; bf16* O; const bf16* BT; const float* bias;
    if (blockIdx.z == 0) { A = tab.inC[l]; O = tab.outC[l]; BT = Wc; bias = bc; }
    else                 { A = tab.inB[l]; O = tab.outB[l]; BT = Wb; bias = bb; }

    const int W   = 1 << lw;
    const int Wp  = W + 2;
    const int HW  = 1 << lhw;
    const int tid = threadIdx.x;
    const int m_base = (local >> 1) * 128;
    const int n0     = (local & 1) * 128;
    const int b   = m_base >> lhw;
    const int y0  = (m_base & (HW - 1)) >> lw;     // tile = R image rows
    const int ibase = b * (H + 2) * Wp * 256;

    // LDS: A = 160 px rows x 64ch (10240 elems), B = 128 co x 64 (8192)
    // -> 18432 elems = 36 KB, 4 blocks/CU. Epilogue reuses first 16384.
    __shared__ __align__(16) bf16 Sh[18432];
    bf16* Als = Sh;
    bf16* Bls = Sh + 10240;

    const int ch8   = (((tid & 7) ^ ((tid >> 3) & 7)) << 3);
    const int rbase = tid >> 3;
    const int Wp256 = Wp * 256;
    const int npx   = (128 >> lw) * Wp;            // window px: 132/136/144
    // tail slot: exec-uniform issue; clamp OOW lanes' global addr into window
    const int toff  = (128 + rbase < npx) ? 4 * 8192 : 0;
    const int ag0   = ibase + rbase * 256 + ch8;
    int bg[4];
#pragma unroll
    for (int i = 0; i < 4; ++i)
        bg[i] = (n0 + i * 32 + rbase) * 256 + ch8;

    f32x4 acc[4][4];
#pragma unroll
    for (int i = 0; i < 4; ++i)
#pragma unroll
        for (int j = 0; j < 4; ++j)
            acc[i][j] = (f32x4)(0.0f);

    const int lane = tid & 63;
    const int wv   = tid >> 6;
    const int wm   = (wv & 1) * 64;
    const int wn   = (wv >> 1) * 64;
    const int l16  = lane & 15;
    const int quad = lane >> 4;
    // A fragment px-row base per i (excl dx): p(m) = m + 2*(m>>lw) + dx
    int pb[4];
#pragma unroll
    for (int i = 0; i < 4; ++i) {
        const int mm = wm + i * 16;
        pb[i] = mm + ((mm >> lw) << 1) + l16;
    }
    const int bRow = (wn + l16) * 64;
    const int bsw  = l16 & 7;
    bf16* const lA = Als + tid * 8;
    bf16* const lB = Bls + tid * 8;

    auto stageA = [&](int dy, int cq) {
        const int abase = ag0 + (y0 + dy) * Wp256 + (cq << 6);
#pragma unroll
        for (int i = 0; i < 4; ++i)
            gl_lds16(A + abase + i * 8192, lA + i * 2048);
        gl_lds16(A + abase + toff, lA + 4 * 2048);
    };

    // B reg-staging: same global (pre-swizzled) source and same LDS dest
    // bytes as the old gl_lds path -> identical layout.
    bf16x8 breg[4];
    auto loadB = [&](int tap, int cq) {
        const int boff = tap * 65536 + (cq << 6);
#pragma unroll
        for (int i = 0; i < 4; ++i)
            breg[i] = *(const bf16x8*)(BT + bg[i] + boff);
    };
    auto writeB = [&]() {
#pragma unroll
        for (int i = 0; i < 4; ++i)
            *(bf16x8*)(lB + i * 2048) = breg[i];   // compiler waits breg vmcnt
    };

    // prologue: stage A(0,0) + B(0), drain once
    stageA(0, 0);
    loadB(0, 0);
    writeB();
    __syncthreads();

    for (int dy = 0; dy < 3; ++dy)
        for (int cq = 0; cq < 4; ++cq) {
#pragma unroll
            for (int dx = 0; dx < 3; ++dx) {
                int ndy = dy, ncq = cq, ndx = dx + 1;
                if (ndx == 3) { ndx = 0; if (++ncq == 4) { ncq = 0; ++ndy; } }
                const bool more = (ndy < 3);
                // ---- issue next-step B global loads (latency hides under
                //      this step's MFMAs) ----
                if (more) loadB(ndy * 3 + ndx, ncq);
                __builtin_amdgcn_sched_barrier(0);   // loads stay above
                int rowi[4];
#pragma unroll
                for (int i = 0; i < 4; ++i) rowi[i] = pb[i] + dx;
#pragma unroll
                for (int ks = 0; ks < 2; ++ks) {
                    const int qk = quad + ks * 4;
                    bf16x8 af[4], bfv[4];
#pragma unroll
                    for (int i = 0; i < 4; ++i)
                        af[i] = *(const bf16x8*)(Als + (rowi[i] << 6) +
                                                 ((qk ^ (rowi[i] & 7)) << 3));
#pragma unroll
                    for (int j = 0; j < 4; ++j)
                        bfv[j] = *(const bf16x8*)(Bls + bRow + j * 1024 +
                                                  ((qk ^ bsw) << 3));
#pragma unroll
                    for (int i = 0; i < 4; ++i)
#pragma unroll
                        for (int j = 0; j < 4; ++j)
                            acc[i][j] = __builtin_amdgcn_mfma_f32_16x16x32_bf16(
                                af[i], bfv[j], acc[i][j], 0, 0, 0);
                }
                __builtin_amdgcn_sched_barrier(0);   // reads stay above
                __builtin_amdgcn_s_barrier();        // trailing: reads done
                __builtin_amdgcn_sched_barrier(0);   // writes stay below
                if (more) {
                    if (ndx == 0) stageA(ndy, ncq);  // next A window (gl_lds)
                    writeB();                        // regs -> B buffer
                    __syncthreads();                 // leading: writes+A ready
                }
            }
        }

    // ---- epilogue: bias+relu+cvt -> wave-private swizzled T -> 16B stores
    float bv[4];
#pragma unroll
    for (int j = 0; j < 4; ++j) bv[j] = bias[n0 + wn + j * 16 + l16];
    bf16* Tw = Sh + wv * 4096;                    // 64x64 bf16, chunk-swizzled
#pragma unroll
    for (int i = 0; i < 4; ++i)
#pragma unroll
        for (int r = 0; r < 4; ++r) {
            const int row = i * 16 + quad * 4 + r;
#pragma unroll
            for (int j = 0; j < 4; ++j) {
                float v = acc[i][j][r] + bv[j];
                v = v > 0.0f ? v : 0.0f;
                const int sc = (((j * 2 + (l16 >> 3)) ^ (row & 7)) << 3) + (l16 & 7);
                Tw[row * 64 + sc] = (bf16)v;
            }
        }
    __syncthreads();
    const int rgrp = lane >> 3, cc = lane & 7;
#pragma unroll
    for (int p = 0; p < 8; ++p) {
        const int row = p * 8 + rgrp;
        bf16x8 vv = *(const bf16x8*)(Tw + row * 64 + ((cc ^ (row & 7)) << 3));
        const int ml = wm + row;
        const int y  = y0 + (ml >> lw);
        const int x  = ml & (W - 1);
        *(bf16x8*)(O + ibase + ((y + 1) * Wp + (x + 1)) * 256 + n0 + wn + cc * 8) = vv;
    }
}

// ---------------------------------------------------------------------------
// Fused prediction conv (cls 80 cols from cls-feat + box/ctr 5 cols from
// box-feat). M-tile 128; writes fp32 straight into d_out (B,5376,85).
// ---------------------------------------------------------------------------
__global__ __launch_bounds__(256) void pred_conv_kernel(
    PredTab tab, const bf16* __restrict__ BT, const float* __restrict__ bias,
    float* __restrict__ out)
{
    const int bx = blockIdx.x;
    const int l  = (bx >= tab.xend0) + (bx >= tab.xend1);
    const int start = (l == 0) ? 0 : (l == 1 ? tab.xend0 : tab.xend1);
    const int mt = bx - start;
    const int H = tab.H[l], lw = tab.lw[l], lhw = tab.lhw[l], off_l = tab.offl[l];
    const bf16* Ac = tab.inC[l];
    const bf16* Ab = tab.inB[l];

    const int W   = 1 << lw;
    const int Wp  = W + 2;
    const int HW  = 1 << lhw;
    const int tid = threadIdx.x;
    const int m_base = mt * 128;
    const int b   = m_base >> lhw;
    const int mi  = m_base & (HW - 1);
    const int y0  = mi >> lw;
    const int ibase = b * (H + 2) * Wp * 256;

    __shared__ __align__(16) bf16 Sh[(128 + 128 + 96) * 64];  // Ac|Ab|B

    const int ch8   = (((tid & 7) ^ ((tid >> 3) & 7)) << 3);
    const int rbase = tid >> 3;
    int ag[4], bg[3];
#pragma unroll
    for (int i = 0; i < 4; ++i) {
        int row = i * 32 + rbase;
        int y = y0 + (row >> lw);
        int x = row & (W - 1);
        ag[i] = ibase + (y * Wp + x) * 256 + ch8;
    }
#pragma unroll
    for (int i = 0; i < 3; ++i)
        bg[i] = (i * 32 + rbase) * 256 + ch8;

    f32x4 accC[2][5], accB[2];
#pragma unroll
    for (int i = 0; i < 2; ++i) {
#pragma unroll
        for (int j = 0; j < 5; ++j) accC[i][j] = (f32x4)(0.0f);
        accB[i] = (f32x4)(0.0f);
    }

    const int lane = tid & 63;
    const int wv   = tid >> 6;
    const int l16  = lane & 15;
    const int quad = lane >> 4;
    const int xsw  = l16 & 7;
    const int aRow = (wv * 32 + l16) * 64;
    bf16* lS = Sh + tid * 8;

    for (int kc = 0; kc < 36; ++kc) {
        const int t  = kc >> 2;
        const int dy = t / 3;
        const int dx = t - dy * 3;
        const int c0 = (kc & 3) << 6;
        const int aoff = (dy * Wp + dx) * 256 + c0;
        const int boff = t * 24576 + c0;          // t*96*256
#pragma unroll
        for (int i = 0; i < 4; ++i)
            gl_lds16(Ac + ag[i] + aoff, lS + i * 2048);
#pragma unroll
        for (int i = 0; i < 4; ++i)
            gl_lds16(Ab + ag[i] + aoff, lS + (4 + i) * 2048);
#pragma unroll
        for (int i = 0; i < 3; ++i)
            gl_lds16(BT + bg[i] + boff, lS + (8 + i) * 2048);
        __syncthreads();
#pragma unroll
        for (int ks = 0; ks < 2; ++ks) {
            const int cO = (((quad + ks * 4) ^ xsw) << 3);
            bf16x8 afc[2], afb[2], bfv[5], bfb;
#pragma unroll
            for (int i = 0; i < 2; ++i) {
                afc[i] = *(const bf16x8*)(Sh + aRow + i * 1024 + cO);
                afb[i] = *(const bf16x8*)(Sh + 8192 + aRow + i * 1024 + cO);
            }
#pragma unroll
            for (int j = 0; j < 5; ++j)
                bfv[j] = *(const bf16x8*)(Sh + 16384 + (j * 16 + l16) * 64 + cO);
            bfb = *(const bf16x8*)(Sh + 16384 + (80 + l16) * 64 + cO);
#pragma unroll
            for (int i = 0; i < 2; ++i) {
#pragma unroll
                for (int j = 0; j < 5; ++j)
                    accC[i][j] = __builtin_amdgcn_mfma_f32_16x16x32_bf16(
                        afc[i], bfv[j], accC[i][j], 0, 0, 0);
                accB[i] = __builtin_amdgcn_mfma_f32_16x16x32_bf16(
                    afb[i], bfb, accB[i], 0, 0, 0);
            }
        }
        __syncthreads();
    }

#pragma unroll
    for (int i = 0; i < 2; ++i) {
#pragma unroll
        for (int r = 0; r < 4; ++r) {
            const int ml  = wv * 32 + i * 16 + quad * 4 + r;
            const int pos = mi + ml;
            const int ob  = (b * 5376 + off_l + pos) * 85;
#pragma unroll
            for (int j = 0; j < 5; ++j)
                out[ob + j * 16 + l16] = accC[i][j][r] + bias[j * 16 + l16];
            if (l16 < 5)
                out[ob + 80 + l16] = accB[i][r] + bias[80 + l16];
        }
    }
}

// ---------------------------------------------------------------------------
// Init: fp32 NCHW -> padded NHWC bf16 via LDS transpose (coalesced both sides)
// One dispatch for all levels; job = b*H + y (one output row).
// ---------------------------------------------------------------------------
__global__ __launch_bounds__(256) void cast_pad_kernel(CastTab tb)
{
    const int bx = blockIdx.x;
    const int l  = (bx >= tb.xend0) + (bx >= tb.xend1);
    const int start = (l == 0) ? 0 : (l == 1 ? tb.xend0 : tb.xend1);
    const int job = bx - start;
    const int H = tb.H[l], lw = tb.lw[l];
    const int W = 1 << lw, Wp = W + 2;
    const int b = job >> lw;               // H == W for all levels
    const int y = job & (W - 1);
    const float* in = tb.in[l] + ((size_t)(b * 256) * H + y) * W;
    bf16* out = tb.out[l] + ((size_t)(b * (H + 2) + y + 1) * Wp + 1) * 256;
    const int tid = threadIdx.x;
    __shared__ bf16 L[16384];              // [x][c], chunk-swizzled by x&31
    const int cpp = 256 >> lw;             // c rows per pass
    const int x = tid & (W - 1);
    const int cb0 = tid >> lw;
    for (int p = 0; p < W; ++p) {
        const int c = p * cpp + cb0;
        float v = in[(size_t)c * H * W + x];
        L[x * 256 + ((((c >> 3) ^ (x & 31))) << 3) + (c & 7)] = (bf16)v;
    }
    __syncthreads();
    const int wpass = W >> 3;
    for (int q = 0; q < wpass; ++q) {
        const int id = q * 256 + tid;
        const int xo = id >> 5;
        const int k  = id & 31;
        bf16x8 vv = *(const bf16x8*)(L + xo * 256 + ((k ^ (xo & 31)) << 3));
        *(bf16x8*)(out + xo * 256 + k * 8) = vv;
    }
}

// zero borders of 5 contiguous padded buffers, all levels in one dispatch
__global__ void border_zero_kernel(BZTab tb)
{
    const int bx = blockIdx.x;
    const int l  = (bx >= tb.xend0) + (bx >= tb.xend1);
    const int start = (l == 0) ? 0 : (l == 1 ? tb.xend0 : tb.xend1);
    const int i   = bx - start;
    const int buf = blockIdx.y;
    const int c   = threadIdx.x;
    const int H = tb.H[l];
    const int ppi = tb.ppi[l];
    const int img = i / ppi;
    const int p   = i - img * ppi;
    const int Wp  = H + 2, Hp = H + 2;
    int y, xp;
    if (p < Wp)            { y = 0;      xp = p; }
    else if (p < 2 * Wp)   { y = Hp - 1; xp = p - Wp; }
    else { int q = p - 2 * Wp; y = 1 + (q >> 1); xp = (q & 1) ? (Wp - 1) : 0; }
    tb.base[l][buf * tb.bufE[l] + ((size_t)(img * Hp + y) * Wp + xp) * 256 + c]
        = (bf16)0.0f;
}

// all weight prepacks in one dispatch:
//  [0,9216) stem cls, [9216,18432) stem box, [18432,19296) pred [t][96][256]
__global__ void prepack_kernel(const float* __restrict__ scw,
                               const float* __restrict__ sbw,
                               const float* __restrict__ pcw,
                               const float* __restrict__ pbw,
                               const float* __restrict__ prw,
                               const float* __restrict__ pcb,
                               const float* __restrict__ pbb,
                               const float* __restrict__ prb,
                               bf16* __restrict__ wc, bf16* __restrict__ wb,
                               bf16* __restrict__ pT, float* __restrict__ pB)
{
    const int ci = threadIdx.x;
    int g = blockIdx.x;
    if (g < 18432) {
        const float* w = (g < 9216) ? scw : sbw;
        bf16* o        = (g < 9216) ? wc  : wb;
        if (g >= 9216) g -= 9216;
        const int co = g & 255;
        const int st = g >> 8;
        const int s  = st / 9;
        const int t  = st - s * 9;
        o[(size_t)g * 256 + ci] = (bf16)w[(((s * 256 + co) * 256 + ci) * 9) + t];
    } else {
        g -= 18432;
        const int t  = g / 96;
        const int co = g - t * 96;
        float v = 0.0f;
        if (co < 80)       v = pcw[((co * 256 + ci) * 9) + t];
        else if (co < 84)  v = pbw[(((co - 80) * 256 + ci) * 9) + t];
        else if (co == 84) v = prw[(ci * 9) + t];
        pT[(size_t)g * 256 + ci] = (bf16)v;
        if (g == 0 && ci < 96) {
            float bvv = 0.0f;
            if (ci < 80)       bvv = pcb[ci];
            else if (ci < 84)  bvv = pbb[ci - 80];
            else if (ci == 84) bvv = prb[0];
            pB[ci] = bvv;
        }
    }
}

// ---------------------------------------------------------------------------
extern "C" void kernel_launch(void* const* d_in, const int* in_sizes, int n_in,
                              void* d_out, int out_size, void* d_ws, size_t ws_size,
                              hipStream_t stream)
{
    (void)in_sizes; (void)n_in; (void)out_size;
    const float* feat[3] = {(const float*)d_in[0], (const float*)d_in[1],
                            (const float*)d_in[2]};
    const float* scw = (const float*)d_in[3];
    const float* scb = (const float*)d_in[4];
    const float* sbw = (const float*)d_in[5];
    const float* sbb = (const float*)d_in[6];
    const float* pcw = (const float*)d_in[7];
    const float* pcb = (const float*)d_in[8];
    const float* pbw = (const float*)d_in[9];
    const float* pbb = (const float*)d_in[10];
    const float* prw = (const float*)d_in[11];
    const float* prb = (const float*)d_in[12];
    float* out = (float*)d_out;

    const int Hs[3]   = {64, 32, 16};
    const int lws[3]  = {6, 5, 4};
    const int lhws[3] = {12, 10, 8};
    const int offl[3] = {0, 4096, 5120};
    const int mtiles[3] = {512, 128, 32};          // M/128 per level
    size_t bufB[3];
    for (int l = 0; l < 3; ++l)
        bufB[l] = (size_t)16 * (Hs[l] + 2) * (Hs[l] + 2) * 256 * 2;

    const size_t WSTEM = (size_t)4 * 9 * 256 * 256 * 2;
    const size_t WPRED = (size_t)9 * 96 * 256 * 2;
    const size_t FULL   = 5 * (bufB[0] + bufB[1] + bufB[2]) + 2 * WSTEM + WPRED + 384;
    const size_t SHARED = 5 * bufB[0] + 2 * WSTEM + WPRED + 384;
    if (ws_size < SHARED) return;
    const bool fused = ws_size >= FULL;

    char* ws = (char*)d_ws;
    bf16* act[3][5];
    size_t off = 0;
    if (fused) {
        for (int l = 0; l < 3; ++l)
            for (int k = 0; k < 5; ++k) { act[l][k] = (bf16*)(ws + off); off += bufB[l]; }
    } else {
        for (int k = 0; k < 5; ++k)
            for (int l = 0; l < 3; ++l) act[l][k] = (bf16*)(ws + (size_t)k * bufB[0]);
        off = 5 * bufB[0];
    }
    bf16*  wbTc = (bf16*)(ws + off); off += WSTEM;
    bf16*  wbTb = (bf16*)(ws + off); off += WSTEM;
    bf16*  pT   = (bf16*)(ws + off); off += WPRED;
    float* pB   = (float*)(ws + off);

    prepack_kernel<<<dim3(19296), 256, 0, stream>>>(scw, sbw, pcw, pbw, prw,
                                                    pcb, pbb, prb,
                                                    wbTc, wbTb, pT, pB);

    auto make_stem_tab = [&](int s, int nlev, const int* levs) {
        StemTab tb{};
        for (int i = 0; i < nlev; ++i) {
            int l = levs[i];
            tb.inC[i]  = (s == 0) ? act[l][0] : ((s & 1) ? act[l][1] : act[l][2]);
            tb.inB[i]  = (s == 0) ? act[l][0] : ((s & 1) ? act[l][3] : act[l][4]);
            tb.outC[i] = (s & 1) ? act[l][2] : act[l][1];
            tb.outB[i] = (s & 1) ? act[l][4] : act[l][3];
            tb.H[i] = Hs[l]; tb.lw[i] = lws[l]; tb.lhw[i] = lhws[l];
        }
        return tb;
    };

    if (fused) {
        // border-zero: one dispatch, all levels x 5 bufs
        BZTab bz{};
        int bpx[3];
        for (int l = 0; l < 3; ++l) {
            bz.base[l] = act[l][0]; bz.H[l] = Hs[l]; bz.bufE[l] = bufB[l] / 2;
            bpx[l] = 2 * (Hs[l] + 2) + 2 * Hs[l];
            bz.ppi[l] = bpx[l];
        }
        bz.xend0 = 16 * bpx[0]; bz.xend1 = bz.xend0 + 16 * bpx[1];
        const int bztot = bz.xend1 + 16 * bpx[2];
        border_zero_kernel<<<dim3(bztot, 5), 256, 0, stream>>>(bz);

        // cast: one dispatch, all levels
        CastTab ct{};
        for (int l = 0; l < 3; ++l) {
            ct.in[l] = feat[l]; ct.out[l] = act[l][0];
            ct.H[l] = Hs[l]; ct.lw[l] = lws[l];
        }
        ct.xend0 = 16 * Hs[0]; ct.xend1 = ct.xend0 + 16 * Hs[1];
        cast_pad_kernel<<<dim3(ct.xend1 + 16 * Hs[2]), 256, 0, stream>>>(ct);

        const int levs[3] = {0, 1, 2};
        const int tx0 = mtiles[0] * 2, tx1 = mtiles[1] * 2, tx2 = mtiles[2] * 2;
        for (int s = 0; s < 4; ++s) {
            StemTab tb = make_stem_tab(s, 3, levs);
            tb.xend0 = tx0; tb.xend1 = tx0 + tx1;
            stem_conv_kernel<<<dim3(tx0 + tx1 + tx2, 1, 2), 256, 0, stream>>>(
                tb, wbTc + (size_t)s * 589824, wbTb + (size_t)s * 589824,
                scb + s * 256, sbb + s * 256);
        }
        PredTab pt{};
        for (int l = 0; l < 3; ++l) {
            pt.inC[l] = act[l][2]; pt.inB[l] = act[l][4];
            pt.H[l] = Hs[l]; pt.lw[l] = lws[l]; pt.lhw[l] = lhws[l]; pt.offl[l] = offl[l];
        }
        pt.xend0 = mtiles[0]; pt.xend1 = mtiles[0] + mtiles[1];
        pred_conv_kernel<<<dim3(mtiles[0] + mtiles[1] + mtiles[2]), 256, 0, stream>>>(
            pt, pT, pB, out);
    } else {
        for (int l = 0; l < 3; ++l) {
            const int bpx = 2 * (Hs[l] + 2) + 2 * Hs[l];
            BZTab bz{};
            bz.base[0] = act[l][0]; bz.H[0] = Hs[l]; bz.bufE[0] = bufB[0] / 2;
            bz.ppi[0] = bpx; bz.xend0 = 16 * bpx; bz.xend1 = 16 * bpx;
            border_zero_kernel<<<dim3(16 * bpx, 5), 256, 0, stream>>>(bz);
            CastTab ct{};
            ct.in[0] = feat[l]; ct.out[0] = act[l][0];
            ct.H[0] = Hs[l]; ct.lw[0] = lws[l];
            ct.xend0 = 16 * Hs[l]; ct.xend1 = 16 * Hs[l];
            cast_pad_kernel<<<dim3(16 * Hs[l]), 256, 0, stream>>>(ct);

            const int levs[1] = {l};
            const int tiles = mtiles[l] * 2;
            for (int s = 0; s < 4; ++s) {
                StemTab tb = make_stem_tab(s, 1, levs);
                tb.xend0 = tiles; tb.xend1 = tiles;
                stem_conv_kernel<<<dim3(tiles, 1, 2), 256, 0, stream>>>(
                    tb, wbTc + (size_t)s * 589824, wbTb + (size_t)s * 589824,
                    scb + s * 256, sbb + s * 256);
            }
            PredTab pt{};
            pt.inC[0] = act[l][2]; pt.inB[0] = act[l][4];
            pt.H[0] = Hs[l]; pt.lw[0] = lws[l]; pt.lhw[0] = lhws[l]; pt.offl[0] = offl[l];
            pt.xend0 = mtiles[l]; pt.xend1 = mtiles[l];
            pred_conv_kernel<<<dim3(mtiles[l]), 256, 0, stream>>>(pt, pT, pB, out);
        }
    }
}

// Round 8
// 936.129 us; speedup vs baseline: 1.1750x; 1.1750x over previous
//
#include <hip/hip_runtime.h>

// ---------------------------------------------------------------------------
// FCOS head on MI355X: bf16 MFMA implicit-GEMM 3x3 convs.
//   activations: padded NHWC bf16, [B][H+2][W+2][256], zero borders
//   stem weights: [s][tap][co][ci] bf16 (B^T, row-contiguous in ci)
//   pred weights: [tap][96][ci] bf16 (rows 0..79 cls, 80..83 box, 84 ctr, pad)
//
// R2: XOR chunk-swizzled LDS -> bank conflicts 5.66e7 -> 0 (verified).
// R3: vectorized epilogue via wave-private LDS transpose; level-fused grids.
// R5: tap-row A staging + exec-uniform tail slot w/ per-lane global clamp.
//     Stem = 128x128 tile, 256 thr, 36KB LDS, 4 blk/CU: 192 us, MfmaUtil 46.
// R6: BN=256 variant regressed 2x. R7/R8: dbuf+syncthreads 286us. R9: forced
//     launch_bounds spill 1531us. R10: B-dbuf counted vmcnt 202us (12 waves).
//     R13: reg-staged B 226us (MFMA phase too short to hide B latency).
//     CONCLUSION: R5's stage->drain->compute at 16 waves/CU is the stem's
//     local optimum; 2688 blocks/1024 slots = 87.5% tail eff; in-block ~53%
//     vs ~62% LDS-pipe ceiling. Stem REVERTED TO R5 EXACTLY.
// R14: pred kernel window-staging (stem's technique): stage Ac+Ab windows
//     (144 rows x 64ch, fixed tail @trow) once per (dy,cq) covering all 3
//     dx taps, B per tap. Staging 132KB -> 72KB per (dy,cq) (-45%), gl_lds
//     33 -> 19. LDS 44 -> 48KB (still 3 blk/CU). Predict pred ~70 -> ~50us,
//     total ~950-975.
// ---------------------------------------------------------------------------

typedef __bf16 bf16;
typedef __attribute__((ext_vector_type(8))) __bf16 bf16x8;
typedef __attribute__((ext_vector_type(4))) float f32x4;

typedef unsigned int uint32_as1 __attribute__((address_space(1)));
typedef unsigned int uint32_as3 __attribute__((address_space(3)));

__device__ __forceinline__ void gl_lds16(const bf16* g, bf16* l) {
    __builtin_amdgcn_global_load_lds(
        (const uint32_as1*)(unsigned long long)g,
        (uint32_as3*)(unsigned int)(unsigned long long)l,
        16, 0, 0);
}

struct StemTab {
    const bf16* inC[3]; const bf16* inB[3];
    bf16* outC[3]; bf16* outB[3];
    int H[3]; int lw[3]; int lhw[3];
    int xend0, xend1;
};
struct PredTab {
    const bf16* inC[3]; const bf16* inB[3];
    int H[3]; int lw[3]; int lhw[3]; int offl[3];
    int xend0, xend1;
};
struct CastTab {
    const float* in[3]; bf16* out[3];
    int H[3]; int lw[3];
    int xend0, xend1;
};
struct BZTab {
    bf16* base[3]; int H[3]; size_t bufE[3]; int ppi[3];
    int xend0, xend1;
};

// ---------------------------------------------------------------------------
// Stem conv (R5, proven): 128x128 tile, 4 waves (2x2 of 64x64), dual-path
// via z, fused levels. K-loop: dy(3) x cq(4) x dx(3); A staged once per
// (dy,cq); stage -> __syncthreads -> compute -> __syncthreads.
// ---------------------------------------------------------------------------
__global__ __launch_bounds__(256) void stem_conv_kernel(
    StemTab tab, const bf16* __restrict__ Wc, const bf16* __restrict__ Wb,
    const float* __restrict__ bc, const float* __restrict__ bb)
{
    const int bx = blockIdx.x;
    const int l  = (bx >= tab.xend0) + (bx >= tab.xend1);
    const int start = (l == 0) ? 0 : (l == 1 ? tab.xend0 : tab.xend1);
    const int local = bx - start;
    const int H = tab.H[l], lw = tab.lw[l], lhw = tab.lhw[l];

    const bf16* A; bf16* O; const bf16* BT; const float* bias;
    if (blockIdx.z == 0) { A = tab.inC[l]; O = tab.outC[l]; BT = Wc; bias = bc; }
    else                 { A = tab.inB[l]; O = tab.outB[l]; BT = Wb; bias = bb; }

    const int W   = 1 << lw;
    const int Wp  = W + 2;
    const int HW  = 1 << lhw;
    const int tid = threadIdx.x;
    const int m_base = (local >> 1) * 128;
    const int n0     = (local & 1) * 128;
    const int b   = m_base >> lhw;
    const int y0  = (m_base & (HW - 1)) >> lw;     // tile = R image rows
    const int ibase = b * (H + 2) * Wp * 256;

    // LDS: A = 160 px rows x 64ch (10240 elems), B = 128 co rows x 64 (8192)
    __shared__ __align__(16) bf16 Sh[18432];
    bf16* Als = Sh;
    bf16* Bls = Sh + 10240;

    const int ch8   = (((tid & 7) ^ ((tid >> 3) & 7)) << 3);
    const int rbase = tid >> 3;
    const int Wp256 = Wp * 256;
    const int npx   = (128 >> lw) * Wp;            // window px: 132/136/144
    // tail slot: exec-uniform issue; clamp OOW lanes' global addr into window
    const int toff  = (128 + rbase < npx) ? 4 * 8192 : 0;
    const int ag0   = ibase + rbase * 256 + ch8;
    int bg[4];
#pragma unroll
    for (int i = 0; i < 4; ++i)
        bg[i] = (n0 + i * 32 + rbase) * 256 + ch8;

    f32x4 acc[4][4];
#pragma unroll
    for (int i = 0; i < 4; ++i)
#pragma unroll
        for (int j = 0; j < 4; ++j)
            acc[i][j] = (f32x4)(0.0f);

    const int lane = tid & 63;
    const int wv   = tid >> 6;
    const int wm   = (wv & 1) * 64;
    const int wn   = (wv >> 1) * 64;
    const int l16  = lane & 15;
    const int quad = lane >> 4;
    // A fragment px-row base per i (excl dx): p(m) = m + 2*(m>>lw) + dx
    int pb[4];
#pragma unroll
    for (int i = 0; i < 4; ++i) {
        const int mm = wm + i * 16;
        pb[i] = mm + ((mm >> lw) << 1) + l16;
    }
    const int bRow = (wn + l16) * 64;
    const int bsw  = l16 & 7;
    bf16* lA = Als + tid * 8;
    bf16* lB = Bls + tid * 8;

    for (int dy = 0; dy < 3; ++dy) {
        const int abase = ag0 + (y0 + dy) * Wp256;
        for (int cq = 0; cq < 4; ++cq) {
            const int c0 = cq << 6;
            // ---- stage A window: R*(W+2) px, contiguous in global ----
#pragma unroll
            for (int i = 0; i < 4; ++i)
                gl_lds16(A + abase + c0 + i * 8192, lA + i * 2048);
            gl_lds16(A + abase + c0 + toff, lA + 4 * 2048);
            for (int dx = 0; dx < 3; ++dx) {
                const int boff = (dy * 3 + dx) * 65536 + c0;
#pragma unroll
                for (int i = 0; i < 4; ++i)
                    gl_lds16(BT + bg[i] + boff, lB + i * 2048);
                __syncthreads();
                int rowi[4];
#pragma unroll
                for (int i = 0; i < 4; ++i) rowi[i] = pb[i] + dx;
#pragma unroll
                for (int ks = 0; ks < 2; ++ks) {
                    const int qk = quad + ks * 4;
                    bf16x8 af[4], bfv[4];
#pragma unroll
                    for (int i = 0; i < 4; ++i)
                        af[i] = *(const bf16x8*)(Als + (rowi[i] << 6) +
                                                 ((qk ^ (rowi[i] & 7)) << 3));
#pragma unroll
                    for (int j = 0; j < 4; ++j)
                        bfv[j] = *(const bf16x8*)(Bls + bRow + j * 1024 +
                                                  ((qk ^ bsw) << 3));
#pragma unroll
                    for (int i = 0; i < 4; ++i)
#pragma unroll
                        for (int j = 0; j < 4; ++j)
                            acc[i][j] = __builtin_amdgcn_mfma_f32_16x16x32_bf16(
                                af[i], bfv[j], acc[i][j], 0, 0, 0);
                }
                __syncthreads();
            }
        }
    }

    // ---- epilogue: bias+relu+cvt -> wave-private swizzled T -> 16B stores
    float bv[4];
#pragma unroll
    for (int j = 0; j < 4; ++j) bv[j] = bias[n0 + wn + j * 16 + l16];
    bf16* Tw = Sh + wv * 4096;                    // 64x64 bf16, chunk-swizzled
#pragma unroll
    for (int i = 0; i < 4; ++i)
#pragma unroll
        for (int r = 0; r < 4; ++r) {
            const int row = i * 16 + quad * 4 + r;
#pragma unroll
            for (int j = 0; j < 4; ++j) {
                float v = acc[i][j][r] + bv[j];
                v = v > 0.0f ? v : 0.0f;
                const int sc = (((j * 2 + (l16 >> 3)) ^ (row & 7)) << 3) + (l16 & 7);
                Tw[row * 64 + sc] = (bf16)v;
            }
        }
    __syncthreads();
    const int rgrp = lane >> 3, cc = lane & 7;
#pragma unroll
    for (int p = 0; p < 8; ++p) {
        const int row = p * 8 + rgrp;
        bf16x8 vv = *(const bf16x8*)(Tw + row * 64 + ((cc ^ (row & 7)) << 3));
        const int ml = wm + row;
        const int y  = y0 + (ml >> lw);
        const int x  = ml & (W - 1);
        *(bf16x8*)(O + ibase + ((y + 1) * Wp + (x + 1)) * 256 + n0 + wn + cc * 8) = vv;
    }
}

// ---------------------------------------------------------------------------
// Fused prediction conv (R14): window-staged. cls 80 cols from cls-feat +
// box/ctr 5 cols from box-feat. M-tile 128, 4 waves of 32 rows each.
// Ac/Ab windows (144 rows x 64ch) staged once per (dy,cq) covering all 3 dx;
// B (96x64) staged per tap. Writes fp32 straight into d_out (B,5376,85).
// LDS: Ac[0,9216) | Ab[9216,18432) | B[18432,24576) = 48KB, 3 blk/CU.
// ---------------------------------------------------------------------------
__global__ __launch_bounds__(256) void pred_conv_kernel(
    PredTab tab, const bf16* __restrict__ BT, const float* __restrict__ bias,
    float* __restrict__ out)
{
    const int bx = blockIdx.x;
    const int l  = (bx >= tab.xend0) + (bx >= tab.xend1);
    const int start = (l == 0) ? 0 : (l == 1 ? tab.xend0 : tab.xend1);
    const int mt = bx - start;
    const int H = tab.H[l], lw = tab.lw[l], lhw = tab.lhw[l], off_l = tab.offl[l];
    const bf16* Ac = tab.inC[l];
    const bf16* Ab = tab.inB[l];

    const int W   = 1 << lw;
    const int Wp  = W + 2;
    const int HW  = 1 << lhw;
    const int tid = threadIdx.x;
    const int m_base = mt * 128;
    const int b   = m_base >> lhw;
    const int mi  = m_base & (HW - 1);
    const int y0  = mi >> lw;
    const int ibase = b * (H + 2) * Wp * 256;

    __shared__ __align__(16) bf16 Sh[24576];   // Ac win | Ab win | B tap

    const int ch8   = (((tid & 7) ^ ((tid >> 3) & 7)) << 3);
    const int rbase = tid >> 3;
    const int Wp256 = Wp * 256;
    const int npx   = (128 >> lw) * Wp;        // 132/136/144
    // fixed tail chunk rows [trow, trow+32): 8-aligned (keeps swizzle phase);
    // covers up to row 143; <=4-row overread past window stays inside d_ws.
    const int trow  = (npx - 25) & ~7;         // 104/104/112
    const int ag0   = ibase + rbase * 256 + ch8;
    int bg[3];
#pragma unroll
    for (int i = 0; i < 3; ++i)
        bg[i] = (i * 32 + rbase) * 256 + ch8;

    f32x4 accC[2][5], accB[2];
#pragma unroll
    for (int i = 0; i < 2; ++i) {
#pragma unroll
        for (int j = 0; j < 5; ++j) accC[i][j] = (f32x4)(0.0f);
        accB[i] = (f32x4)(0.0f);
    }

    const int lane = tid & 63;
    const int wv   = tid >> 6;
    const int l16  = lane & 15;
    const int quad = lane >> 4;
    // A fragment px-row base per i (excl dx): rows ml = wv*32 + i*16 + l16
    int pbp[2];
#pragma unroll
    for (int i = 0; i < 2; ++i) {
        const int mm = wv * 32 + i * 16;
        pbp[i] = mm + ((mm >> lw) << 1) + l16;
    }
    const int bsw = l16 & 7;
    bf16* const lAc = Sh + tid * 8;
    bf16* const lAb = Sh + 9216 + tid * 8;
    bf16* const lB  = Sh + 18432 + tid * 8;
    bf16* const lAcT = Sh + trow * 64 + tid * 8;
    bf16* const lAbT = Sh + 9216 + trow * 64 + tid * 8;

    for (int dy = 0; dy < 3; ++dy) {
        for (int cq = 0; cq < 4; ++cq) {
            const int abase = ag0 + (y0 + dy) * Wp256 + (cq << 6);
            // ---- stage Ac/Ab windows: 4x32-row chunks + fixed tail ----
#pragma unroll
            for (int i = 0; i < 4; ++i) {
                gl_lds16(Ac + abase + i * 8192, lAc + i * 2048);
                gl_lds16(Ab + abase + i * 8192, lAb + i * 2048);
            }
            gl_lds16(Ac + abase + trow * 256, lAcT);
            gl_lds16(Ab + abase + trow * 256, lAbT);
            for (int dx = 0; dx < 3; ++dx) {
                const int boff = (dy * 3 + dx) * 24576 + (cq << 6);
#pragma unroll
                for (int i = 0; i < 3; ++i)
                    gl_lds16(BT + bg[i] + boff, lB + i * 2048);
                __syncthreads();
                int rowi[2];
#pragma unroll
                for (int i = 0; i < 2; ++i) rowi[i] = pbp[i] + dx;
#pragma unroll
                for (int ks = 0; ks < 2; ++ks) {
                    const int qk = quad + ks * 4;
                    bf16x8 afc[2], afb[2], bfv[5], bfb;
#pragma unroll
                    for (int i = 0; i < 2; ++i) {
                        const int sw = ((qk ^ (rowi[i] & 7)) << 3);
                        afc[i] = *(const bf16x8*)(Sh + (rowi[i] << 6) + sw);
                        afb[i] = *(const bf16x8*)(Sh + 9216 + (rowi[i] << 6) + sw);
                    }
                    const int cO = ((qk ^ bsw) << 3);
#pragma unroll
                    for (int j = 0; j < 5; ++j)
                        bfv[j] = *(const bf16x8*)(Sh + 18432 +
                                                  (j * 16 + l16) * 64 + cO);
                    bfb = *(const bf16x8*)(Sh + 18432 + (80 + l16) * 64 + cO);
#pragma unroll
                    for (int i = 0; i < 2; ++i) {
#pragma unroll
                        for (int j = 0; j < 5; ++j)
                            accC[i][j] = __builtin_amdgcn_mfma_f32_16x16x32_bf16(
                                afc[i], bfv[j], accC[i][j], 0, 0, 0);
                        accB[i] = __builtin_amdgcn_mfma_f32_16x16x32_bf16(
                            afb[i], bfb, accB[i], 0, 0, 0);
                    }
                }
                __syncthreads();
            }
        }
    }

#pragma unroll
    for (int i = 0; i < 2; ++i) {
#pragma unroll
        for (int r = 0; r < 4; ++r) {
            const int ml  = wv * 32 + i * 16 + quad * 4 + r;
            const int pos = mi + ml;
            const int ob  = (b * 5376 + off_l + pos) * 85;
#pragma unroll
            for (int j = 0; j < 5; ++j)
                out[ob + j * 16 + l16] = accC[i][j][r] + bias[j * 16 + l16];
            if (l16 < 5)
                out[ob + 80 + l16] = accB[i][r] + bias[80 + l16];
        }
    }
}

// ---------------------------------------------------------------------------
// Init: fp32 NCHW -> padded NHWC bf16 via LDS transpose (coalesced both sides)
// One dispatch for all levels; job = b*H + y (one output row).
// ---------------------------------------------------------------------------
__global__ __launch_bounds__(256) void cast_pad_kernel(CastTab tb)
{
    const int bx = blockIdx.x;
    const int l  = (bx >= tb.xend0) + (bx >= tb.xend1);
    const int start = (l == 0) ? 0 : (l == 1 ? tb.xend0 : tb.xend1);
    const int job = bx - start;
    const int H = tb.H[l], lw = tb.lw[l];
    const int W = 1 << lw, Wp = W + 2;
    const int b = job >> lw;               // H == W for all levels
    const int y = job & (W - 1);
    const float* in = tb.in[l] + ((size_t)(b * 256) * H + y) * W;
    bf16* out = tb.out[l] + ((size_t)(b * (H + 2) + y + 1) * Wp + 1) * 256;
    const int tid = threadIdx.x;
    __shared__ bf16 L[16384];              // [x][c], chunk-swizzled by x&31
    const int cpp = 256 >> lw;             // c rows per pass
    const int x = tid & (W - 1);
    const int cb0 = tid >> lw;
    for (int p = 0; p < W; ++p) {
        const int c = p * cpp + cb0;
        float v = in[(size_t)c * H * W + x];
        L[x * 256 + ((((c >> 3) ^ (x & 31))) << 3) + (c & 7)] = (bf16)v;
    }
    __syncthreads();
    const int wpass = W >> 3;
    for (int q = 0; q < wpass; ++q) {
        const int id = q * 256 + tid;
        const int xo = id >> 5;
        const int k  = id & 31;
        bf16x8 vv = *(const bf16x8*)(L + xo * 256 + ((k ^ (xo & 31)) << 3));
        *(bf16x8*)(out + xo * 256 + k * 8) = vv;
    }
}

// zero borders of 5 contiguous padded buffers, all levels in one dispatch
__global__ void border_zero_kernel(BZTab tb)
{
    const int bx = blockIdx.x;
    const int l  = (bx >= tb.xend0) + (bx >= tb.xend1);
    const int start = (l == 0) ? 0 : (l == 1 ? tb.xend0 : tb.xend1);
    const int i   = bx - start;
    const int buf = blockIdx.y;
    const int c   = threadIdx.x;
    const int H = tb.H[l];
    const int ppi = tb.ppi[l];
    const int img = i / ppi;
    const int p   = i - img * ppi;
    const int Wp  = H + 2, Hp = H + 2;
    int y, xp;
    if (p < Wp)            { y = 0;      xp = p; }
    else if (p < 2 * Wp)   { y = Hp - 1; xp = p - Wp; }
    else { int q = p - 2 * Wp; y = 1 + (q >> 1); xp = (q & 1) ? (Wp - 1) : 0; }
    tb.base[l][buf * tb.bufE[l] + ((size_t)(img * Hp + y) * Wp + xp) * 256 + c]
        = (bf16)0.0f;
}

// all weight prepacks in one dispatch:
//  [0,9216) stem cls, [9216,18432) stem box, [18432,19296) pred [t][96][256]
__global__ void prepack_kernel(const float* __restrict__ scw,
                               const float* __restrict__ sbw,
                               const float* __restrict__ pcw,
                               const float* __restrict__ pbw,
                               const float* __restrict__ prw,
                               const float* __restrict__ pcb,
                               const float* __restrict__ pbb,
                               const float* __restrict__ prb,
                               bf16* __restrict__ wc, bf16* __restrict__ wb,
                               bf16* __restrict__ pT, float* __restrict__ pB)
{
    const int ci = threadIdx.x;
    int g = blockIdx.x;
    if (g < 18432) {
        const float* w = (g < 9216) ? scw : sbw;
        bf16* o        = (g < 9216) ? wc  : wb;
        if (g >= 9216) g -= 9216;
        const int co = g & 255;
        const int st = g >> 8;
        const int s  = st / 9;
        const int t  = st - s * 9;
        o[(size_t)g * 256 + ci] = (bf16)w[(((s * 256 + co) * 256 + ci) * 9) + t];
    } else {
        g -= 18432;
        const int t  = g / 96;
        const int co = g - t * 96;
        float v = 0.0f;
        if (co < 80)       v = pcw[((co * 256 + ci) * 9) + t];
        else if (co < 84)  v = pbw[(((co - 80) * 256 + ci) * 9) + t];
        else if (co == 84) v = prw[(ci * 9) + t];
        pT[(size_t)g * 256 + ci] = (bf16)v;
        if (g == 0 && ci < 96) {
            float bvv = 0.0f;
            if (ci < 80)       bvv = pcb[ci];
            else if (ci < 84)  bvv = pbb[ci - 80];
            else if (ci == 84) bvv = prb[0];
            pB[ci] = bvv;
        }
    }
}

// ---------------------------------------------------------------------------
extern "C" void kernel_launch(void* const* d_in, const int* in_sizes, int n_in,
                              void* d_out, int out_size, void* d_ws, size_t ws_size,
                              hipStream_t stream)
{
    (void)in_sizes; (void)n_in; (void)out_size;
    const float* feat[3] = {(const float*)d_in[0], (const float*)d_in[1],
                            (const float*)d_in[2]};
    const float* scw = (const float*)d_in[3];
    const float* scb = (const float*)d_in[4];
    const float* sbw = (const float*)d_in[5];
    const float* sbb = (const float*)d_in[6];
    const float* pcw = (const float*)d_in[7];
    const float* pcb = (const float*)d_in[8];
    const float* pbw = (const float*)d_in[9];
    const float* pbb = (const float*)d_in[10];
    const float* prw = (const float*)d_in[11];
    const float* prb = (const float*)d_in[12];
    float* out = (float*)d_out;

    const int Hs[3]   = {64, 32, 16};
    const int lws[3]  = {6, 5, 4};
    const int lhws[3] = {12, 10, 8};
    const int offl[3] = {0, 4096, 5120};
    const int mtiles[3] = {512, 128, 32};          // M/128 per level
    size_t bufB[3];
    for (int l = 0; l < 3; ++l)
        bufB[l] = (size_t)16 * (Hs[l] + 2) * (Hs[l] + 2) * 256 * 2;

    const size_t WSTEM = (size_t)4 * 9 * 256 * 256 * 2;
    const size_t WPRED = (size_t)9 * 96 * 256 * 2;
    const size_t FULL   = 5 * (bufB[0] + bufB[1] + bufB[2]) + 2 * WSTEM + WPRED + 384;
    const size_t SHARED = 5 * bufB[0] + 2 * WSTEM + WPRED + 384;
    if (ws_size < SHARED) return;
    const bool fused = ws_size >= FULL;

    char* ws = (char*)d_ws;
    bf16* act[3][5];
    size_t off = 0;
    if (fused) {
        for (int l = 0; l < 3; ++l)
            for (int k = 0; k < 5; ++k) { act[l][k] = (bf16*)(ws + off); off += bufB[l]; }
    } else {
        for (int k = 0; k < 5; ++k)
            for (int l = 0; l < 3; ++l) act[l][k] = (bf16*)(ws + (size_t)k * bufB[0]);
        off = 5 * bufB[0];
    }
    bf16*  wbTc = (bf16*)(ws + off); off += WSTEM;
    bf16*  wbTb = (bf16*)(ws + off); off += WSTEM;
    bf16*  pT   = (bf16*)(ws + off); off += WPRED;
    float* pB   = (float*)(ws + off);

    prepack_kernel<<<dim3(19296), 256, 0, stream>>>(scw, sbw, pcw, pbw, prw,
                                                    pcb, pbb, prb,
                                                    wbTc, wbTb, pT, pB);

    auto make_stem_tab = [&](int s, int nlev, const int* levs) {
        StemTab tb{};
        for (int i = 0; i < nlev; ++i) {
            int l = levs[i];
            tb.inC[i]  = (s == 0) ? act[l][0] : ((s & 1) ? act[l][1] : act[l][2]);
            tb.inB[i]  = (s == 0) ? act[l][0] : ((s & 1) ? act[l][3] : act[l][4]);
            tb.outC[i] = (s & 1) ? act[l][2] : act[l][1];
            tb.outB[i] = (s & 1) ? act[l][4] : act[l][3];
            tb.H[i] = Hs[l]; tb.lw[i] = lws[l]; tb.lhw[i] = lhws[l];
        }
        return tb;
    };

    if (fused) {
        // border-zero: one dispatch, all levels x 5 bufs
        BZTab bz{};
        int bpx[3];
        for (int l = 0; l < 3; ++l) {
            bz.base[l] = act[l][0]; bz.H[l] = Hs[l]; bz.bufE[l] = bufB[l] / 2;
            bpx[l] = 2 * (Hs[l] + 2) + 2 * Hs[l];
            bz.ppi[l] = bpx[l];
        }
        bz.xend0 = 16 * bpx[0]; bz.xend1 = bz.xend0 + 16 * bpx[1];
        const int bztot = bz.xend1 + 16 * bpx[2];
        border_zero_kernel<<<dim3(bztot, 5), 256, 0, stream>>>(bz);

        // cast: one dispatch, all levels
        CastTab ct{};
        for (int l = 0; l < 3; ++l) {
            ct.in[l] = feat[l]; ct.out[l] = act[l][0];
            ct.H[l] = Hs[l]; ct.lw[l] = lws[l];
        }
        ct.xend0 = 16 * Hs[0]; ct.xend1 = ct.xend0 + 16 * Hs[1];
        cast_pad_kernel<<<dim3(ct.xend1 + 16 * Hs[2]), 256, 0, stream>>>(ct);

        const int levs[3] = {0, 1, 2};
        const int tx0 = mtiles[0] * 2, tx1 = mtiles[1] * 2, tx2 = mtiles[2] * 2;
        for (int s = 0; s < 4; ++s) {
            StemTab tb = make_stem_tab(s, 3, levs);
            tb.xend0 = tx0; tb.xend1 = tx0 + tx1;
            stem_conv_kernel<<<dim3(tx0 + tx1 + tx2, 1, 2), 256, 0, stream>>>(
                tb, wbTc + (size_t)s * 589824, wbTb + (size_t)s * 589824,
                scb + s * 256, sbb + s * 256);
        }
        PredTab pt{};
        for (int l = 0; l < 3; ++l) {
            pt.inC[l] = act[l][2]; pt.inB[l] = act[l][4];
            pt.H[l] = Hs[l]; pt.lw[l] = lws[l]; pt.lhw[l] = lhws[l]; pt.offl[l] = offl[l];
        }
        pt.xend0 = mtiles[0]; pt.xend1 = mtiles[0] + mtiles[1];
        pred_conv_kernel<<<dim3(mtiles[0] + mtiles[1] + mtiles[2]), 256, 0, stream>>>(
            pt, pT, pB, out);
    } else {
        for (int l = 0; l < 3; ++l) {
            const int bpx = 2 * (Hs[l] + 2) + 2 * Hs[l];
            BZTab bz{};
            bz.base[0] = act[l][0]; bz.H[0] = Hs[l]; bz.bufE[0] = bufB[0] / 2;
            bz.ppi[0] = bpx; bz.xend0 = 16 * bpx; bz.xend1 = 16 * bpx;
            border_zero_kernel<<<dim3(16 * bpx, 5), 256, 0, stream>>>(bz);
            CastTab ct{};
            ct.in[0] = feat[l]; ct.out[0] = act[l][0];
            ct.H[0] = Hs[l]; ct.lw[0] = lws[l];
            ct.xend0 = 16 * Hs[l]; ct.xend1 = 16 * Hs[l];
            cast_pad_kernel<<<dim3(16 * Hs[l]), 256, 0, stream>>>(ct);

            const int levs[1] = {l};
            const int tiles = mtiles[l] * 2;
            for (int s = 0; s < 4; ++s) {
                StemTab tb = make_stem_tab(s, 1, levs);
                tb.xend0 = tiles; tb.xend1 = tiles;
                stem_conv_kernel<<<dim3(tiles, 1, 2), 256, 0, stream>>>(
                    tb, wbTc + (size_t)s * 589824, wbTb + (size_t)s * 589824,
                    scb + s * 256, sbb + s * 256);
            }
            PredTab pt{};
            pt.inC[0] = act[l][2]; pt.inB[0] = act[l][4];
            pt.H[0] = Hs[l]; pt.lw[0] = lws[l]; pt.lhw[0] = lhws[l]; pt.offl[0] = offl[l];
            pt.xend0 = mtiles[l]; pt.xend1 = mtiles[l];
            pred_conv_kernel<<<dim3(mtiles[l]), 256, 0, stream>>>(pt, pT, pB, out);
        }
    }
}

// Round 9
// 929.102 us; speedup vs baseline: 1.1839x; 1.0076x over previous
//
#include <hip/hip_runtime.h>

// ---------------------------------------------------------------------------
// FCOS head on MI355X: bf16 MFMA implicit-GEMM 3x3 convs.
//   activations: padded NHWC bf16, [B][H+2][W+2][256], zero borders
//   stem weights: [s][tap][co][ci] bf16 (B^T, row-contiguous in ci)
//   pred weights: [tap][96][ci] bf16 (rows 0..79 cls, 80..83 box, 84 ctr, pad)
//
// R2: XOR chunk-swizzled LDS -> bank conflicts 0. R3: vectorized epilogue.
// R5: tap-row A staging; stem 128x128, 36KB LDS, 4 blk/CU: 192us, MfmaUtil 46.
// R6-R13: stem restructures all regressed (dbuf 286, forced-bounds spill 1531,
//     counted-vmcnt 202 @12waves, reg-staged B 226). Stem LDS-BW ceiling
//     arithmetic: 348KB LDS traffic/CU-step @256B/cy = 1360cy vs MFMA 620cy
//     -> MfmaUtil ceiling ~46% = measured. Stem is at structural roofline;
//     kept at R5 exactly.
// R14: pred window-staging (Ac/Ab 144-row windows per (dy,cq), B per tap):
//     WIN, total 992.7 -> 936.1us.
// R15: init-kernel cleanup (stem/pred untouched): border_zero vectorized
//     bf16x8, 8 px/block (36800 -> 4600 blocks); cast_pad float4 reads
//     (4 -> 16 B/lane). Predict total ~895-915us.
// ---------------------------------------------------------------------------

typedef __bf16 bf16;
typedef __attribute__((ext_vector_type(8))) __bf16 bf16x8;
typedef __attribute__((ext_vector_type(4))) float f32x4;

typedef unsigned int uint32_as1 __attribute__((address_space(1)));
typedef unsigned int uint32_as3 __attribute__((address_space(3)));

__device__ __forceinline__ void gl_lds16(const bf16* g, bf16* l) {
    __builtin_amdgcn_global_load_lds(
        (const uint32_as1*)(unsigned long long)g,
        (uint32_as3*)(unsigned int)(unsigned long long)l,
        16, 0, 0);
}

struct StemTab {
    const bf16* inC[3]; const bf16* inB[3];
    bf16* outC[3]; bf16* outB[3];
    int H[3]; int lw[3]; int lhw[3];
    int xend0, xend1;
};
struct PredTab {
    const bf16* inC[3]; const bf16* inB[3];
    int H[3]; int lw[3]; int lhw[3]; int offl[3];
    int xend0, xend1;
};
struct CastTab {
    const float* in[3]; bf16* out[3];
    int H[3]; int lw[3];
    int xend0, xend1;
};
struct BZTab {
    bf16* base[3]; int H[3]; size_t bufE[3]; int ppi[3];
    int xend0, xend1;
};

// ---------------------------------------------------------------------------
// Stem conv (R5, proven): 128x128 tile, 4 waves (2x2 of 64x64), dual-path
// via z, fused levels. K-loop: dy(3) x cq(4) x dx(3); A staged once per
// (dy,cq); stage -> __syncthreads -> compute -> __syncthreads.
// ---------------------------------------------------------------------------
__global__ __launch_bounds__(256) void stem_conv_kernel(
    StemTab tab, const bf16* __restrict__ Wc, const bf16* __restrict__ Wb,
    const float* __restrict__ bc, const float* __restrict__ bb)
{
    const int bx = blockIdx.x;
    const int l  = (bx >= tab.xend0) + (bx >= tab.xend1);
    const int start = (l == 0) ? 0 : (l == 1 ? tab.xend0 : tab.xend1);
    const int local = bx - start;
    const int H = tab.H[l], lw = tab.lw[l], lhw = tab.lhw[l];

    const bf16* A; bf16* O; const bf16* BT; const float* bias;
    if (blockIdx.z == 0) { A = tab.inC[l]; O = tab.outC[l]; BT = Wc; bias = bc; }
    else                 { A = tab.inB[l]; O = tab.outB[l]; BT = Wb; bias = bb; }

    const int W   = 1 << lw;
    const int Wp  = W + 2;
    const int HW  = 1 << lhw;
    const int tid = threadIdx.x;
    const int m_base = (local >> 1) * 128;
    const int n0     = (local & 1) * 128;
    const int b   = m_base >> lhw;
    const int y0  = (m_base & (HW - 1)) >> lw;     // tile = R image rows
    const int ibase = b * (H + 2) * Wp * 256;

    // LDS: A = 160 px rows x 64ch (10240 elems), B = 128 co rows x 64 (8192)
    __shared__ __align__(16) bf16 Sh[18432];
    bf16* Als = Sh;
    bf16* Bls = Sh + 10240;

    const int ch8   = (((tid & 7) ^ ((tid >> 3) & 7)) << 3);
    const int rbase = tid >> 3;
    const int Wp256 = Wp * 256;
    const int npx   = (128 >> lw) * Wp;            // window px: 132/136/144
    // tail slot: exec-uniform issue; clamp OOW lanes' global addr into window
    const int toff  = (128 + rbase < npx) ? 4 * 8192 : 0;
    const int ag0   = ibase + rbase * 256 + ch8;
    int bg[4];
#pragma unroll
    for (int i = 0; i < 4; ++i)
        bg[i] = (n0 + i * 32 + rbase) * 256 + ch8;

    f32x4 acc[4][4];
#pragma unroll
    for (int i = 0; i < 4; ++i)
#pragma unroll
        for (int j = 0; j < 4; ++j)
            acc[i][j] = (f32x4)(0.0f);

    const int lane = tid & 63;
    const int wv   = tid >> 6;
    const int wm   = (wv & 1) * 64;
    const int wn   = (wv >> 1) * 64;
    const int l16  = lane & 15;
    const int quad = lane >> 4;
    // A fragment px-row base per i (excl dx): p(m) = m + 2*(m>>lw) + dx
    int pb[4];
#pragma unroll
    for (int i = 0; i < 4; ++i) {
        const int mm = wm + i * 16;
        pb[i] = mm + ((mm >> lw) << 1) + l16;
    }
    const int bRow = (wn + l16) * 64;
    const int bsw  = l16 & 7;
    bf16* lA = Als + tid * 8;
    bf16* lB = Bls + tid * 8;

    for (int dy = 0; dy < 3; ++dy) {
        const int abase = ag0 + (y0 + dy) * Wp256;
        for (int cq = 0; cq < 4; ++cq) {
            const int c0 = cq << 6;
            // ---- stage A window: R*(W+2) px, contiguous in global ----
#pragma unroll
            for (int i = 0; i < 4; ++i)
                gl_lds16(A + abase + c0 + i * 8192, lA + i * 2048);
            gl_lds16(A + abase + c0 + toff, lA + 4 * 2048);
            for (int dx = 0; dx < 3; ++dx) {
                const int boff = (dy * 3 + dx) * 65536 + c0;
#pragma unroll
                for (int i = 0; i < 4; ++i)
                    gl_lds16(BT + bg[i] + boff, lB + i * 2048);
                __syncthreads();
                int rowi[4];
#pragma unroll
                for (int i = 0; i < 4; ++i) rowi[i] = pb[i] + dx;
#pragma unroll
                for (int ks = 0; ks < 2; ++ks) {
                    const int qk = quad + ks * 4;
                    bf16x8 af[4], bfv[4];
#pragma unroll
                    for (int i = 0; i < 4; ++i)
                        af[i] = *(const bf16x8*)(Als + (rowi[i] << 6) +
                                                 ((qk ^ (rowi[i] & 7)) << 3));
#pragma unroll
                    for (int j = 0; j < 4; ++j)
                        bfv[j] = *(const bf16x8*)(Bls + bRow + j * 1024 +
                                                  ((qk ^ bsw) << 3));
#pragma unroll
                    for (int i = 0; i < 4; ++i)
#pragma unroll
                        for (int j = 0; j < 4; ++j)
                            acc[i][j] = __builtin_amdgcn_mfma_f32_16x16x32_bf16(
                                af[i], bfv[j], acc[i][j], 0, 0, 0);
                }
                __syncthreads();
            }
        }
    }

    // ---- epilogue: bias+relu+cvt -> wave-private swizzled T -> 16B stores
    float bv[4];
#pragma unroll
    for (int j = 0; j < 4; ++j) bv[j] = bias[n0 + wn + j * 16 + l16];
    bf16* Tw = Sh + wv * 4096;                    // 64x64 bf16, chunk-swizzled
#pragma unroll
    for (int i = 0; i < 4; ++i)
#pragma unroll
        for (int r = 0; r < 4; ++r) {
            const int row = i * 16 + quad * 4 + r;
#pragma unroll
            for (int j = 0; j < 4; ++j) {
                float v = acc[i][j][r] + bv[j];
                v = v > 0.0f ? v : 0.0f;
                const int sc = (((j * 2 + (l16 >> 3)) ^ (row & 7)) << 3) + (l16 & 7);
                Tw[row * 64 + sc] = (bf16)v;
            }
        }
    __syncthreads();
    const int rgrp = lane >> 3, cc = lane & 7;
#pragma unroll
    for (int p = 0; p < 8; ++p) {
        const int row = p * 8 + rgrp;
        bf16x8 vv = *(const bf16x8*)(Tw + row * 64 + ((cc ^ (row & 7)) << 3));
        const int ml = wm + row;
        const int y  = y0 + (ml >> lw);
        const int x  = ml & (W - 1);
        *(bf16x8*)(O + ibase + ((y + 1) * Wp + (x + 1)) * 256 + n0 + wn + cc * 8) = vv;
    }
}

// ---------------------------------------------------------------------------
// Fused prediction conv (R14, proven): window-staged. cls 80 cols from
// cls-feat + box/ctr 5 cols from box-feat. M-tile 128, 4 waves of 32 rows.
// Ac/Ab windows (144 rows x 64ch) staged once per (dy,cq) covering all 3 dx;
// B (96x64) staged per tap. Writes fp32 straight into d_out (B,5376,85).
// LDS: Ac[0,9216) | Ab[9216,18432) | B[18432,24576) = 48KB, 3 blk/CU.
// ---------------------------------------------------------------------------
__global__ __launch_bounds__(256) void pred_conv_kernel(
    PredTab tab, const bf16* __restrict__ BT, const float* __restrict__ bias,
    float* __restrict__ out)
{
    const int bx = blockIdx.x;
    const int l  = (bx >= tab.xend0) + (bx >= tab.xend1);
    const int start = (l == 0) ? 0 : (l == 1 ? tab.xend0 : tab.xend1);
    const int mt = bx - start;
    const int H = tab.H[l], lw = tab.lw[l], lhw = tab.lhw[l], off_l = tab.offl[l];
    const bf16* Ac = tab.inC[l];
    const bf16* Ab = tab.inB[l];

    const int W   = 1 << lw;
    const int Wp  = W + 2;
    const int HW  = 1 << lhw;
    const int tid = threadIdx.x;
    const int m_base = mt * 128;
    const int b   = m_base >> lhw;
    const int mi  = m_base & (HW - 1);
    const int y0  = mi >> lw;
    const int ibase = b * (H + 2) * Wp * 256;

    __shared__ __align__(16) bf16 Sh[24576];   // Ac win | Ab win | B tap

    const int ch8   = (((tid & 7) ^ ((tid >> 3) & 7)) << 3);
    const int rbase = tid >> 3;
    const int Wp256 = Wp * 256;
    const int npx   = (128 >> lw) * Wp;        // 132/136/144
    // fixed tail chunk rows [trow, trow+32): 8-aligned (keeps swizzle phase);
    // covers up to row 143; <=4-row overread past window stays inside d_ws.
    const int trow  = (npx - 25) & ~7;         // 104/104/112
    const int ag0   = ibase + rbase * 256 + ch8;
    int bg[3];
#pragma unroll
    for (int i = 0; i < 3; ++i)
        bg[i] = (i * 32 + rbase) * 256 + ch8;

    f32x4 accC[2][5], accB[2];
#pragma unroll
    for (int i = 0; i < 2; ++i) {
#pragma unroll
        for (int j = 0; j < 5; ++j) accC[i][j] = (f32x4)(0.0f);
        accB[i] = (f32x4)(0.0f);
    }

    const int lane = tid & 63;
    const int wv   = tid >> 6;
    const int l16  = lane & 15;
    const int quad = lane >> 4;
    // A fragment px-row base per i (excl dx): rows ml = wv*32 + i*16 + l16
    int pbp[2];
#pragma unroll
    for (int i = 0; i < 2; ++i) {
        const int mm = wv * 32 + i * 16;
        pbp[i] = mm + ((mm >> lw) << 1) + l16;
    }
    const int bsw = l16 & 7;
    bf16* const lAc = Sh + tid * 8;
    bf16* const lAb = Sh + 9216 + tid * 8;
    bf16* const lB  = Sh + 18432 + tid * 8;
    bf16* const lAcT = Sh + trow * 64 + tid * 8;
    bf16* const lAbT = Sh + 9216 + trow * 64 + tid * 8;

    for (int dy = 0; dy < 3; ++dy) {
        for (int cq = 0; cq < 4; ++cq) {
            const int abase = ag0 + (y0 + dy) * Wp256 + (cq << 6);
            // ---- stage Ac/Ab windows: 4x32-row chunks + fixed tail ----
#pragma unroll
            for (int i = 0; i < 4; ++i) {
                gl_lds16(Ac + abase + i * 8192, lAc + i * 2048);
                gl_lds16(Ab + abase + i * 8192, lAb + i * 2048);
            }
            gl_lds16(Ac + abase + trow * 256, lAcT);
            gl_lds16(Ab + abase + trow * 256, lAbT);
            for (int dx = 0; dx < 3; ++dx) {
                const int boff = (dy * 3 + dx) * 24576 + (cq << 6);
#pragma unroll
                for (int i = 0; i < 3; ++i)
                    gl_lds16(BT + bg[i] + boff, lB + i * 2048);
                __syncthreads();
                int rowi[2];
#pragma unroll
                for (int i = 0; i < 2; ++i) rowi[i] = pbp[i] + dx;
#pragma unroll
                for (int ks = 0; ks < 2; ++ks) {
                    const int qk = quad + ks * 4;
                    bf16x8 afc[2], afb[2], bfv[5], bfb;
#pragma unroll
                    for (int i = 0; i < 2; ++i) {
                        const int sw = ((qk ^ (rowi[i] & 7)) << 3);
                        afc[i] = *(const bf16x8*)(Sh + (rowi[i] << 6) + sw);
                        afb[i] = *(const bf16x8*)(Sh + 9216 + (rowi[i] << 6) + sw);
                    }
                    const int cO = ((qk ^ bsw) << 3);
#pragma unroll
                    for (int j = 0; j < 5; ++j)
                        bfv[j] = *(const bf16x8*)(Sh + 18432 +
                                                  (j * 16 + l16) * 64 + cO);
                    bfb = *(const bf16x8*)(Sh + 18432 + (80 + l16) * 64 + cO);
#pragma unroll
                    for (int i = 0; i < 2; ++i) {
#pragma unroll
                        for (int j = 0; j < 5; ++j)
                            accC[i][j] = __builtin_amdgcn_mfma_f32_16x16x32_bf16(
                                afc[i], bfv[j], accC[i][j], 0, 0, 0);
                        accB[i] = __builtin_amdgcn_mfma_f32_16x16x32_bf16(
                            afb[i], bfb, accB[i], 0, 0, 0);
                    }
                }
                __syncthreads();
            }
        }
    }

#pragma unroll
    for (int i = 0; i < 2; ++i) {
#pragma unroll
        for (int r = 0; r < 4; ++r) {
            const int ml  = wv * 32 + i * 16 + quad * 4 + r;
            const int pos = mi + ml;
            const int ob  = (b * 5376 + off_l + pos) * 85;
#pragma unroll
            for (int j = 0; j < 5; ++j)
                out[ob + j * 16 + l16] = accC[i][j][r] + bias[j * 16 + l16];
            if (l16 < 5)
                out[ob + 80 + l16] = accB[i][r] + bias[80 + l16];
        }
    }
}

// ---------------------------------------------------------------------------
// Init (R15): fp32 NCHW -> padded NHWC bf16 via LDS transpose, float4 reads
// (16 B/lane). One dispatch for all levels; job = b*H + y (one output row).
// ---------------------------------------------------------------------------
__global__ __launch_bounds__(256) void cast_pad_kernel(CastTab tb)
{
    const int bx = blockIdx.x;
    const int l  = (bx >= tb.xend0) + (bx >= tb.xend1);
    const int start = (l == 0) ? 0 : (l == 1 ? tb.xend0 : tb.xend1);
    const int job = bx - start;
    const int H = tb.H[l], lw = tb.lw[l];
    const int W = 1 << lw, Wp = W + 2;
    const int b = job >> lw;               // H == W for all levels
    const int y = job & (W - 1);
    const float* in = tb.in[l] + ((size_t)(b * 256) * H + y) * W;
    bf16* out = tb.out[l] + ((size_t)(b * (H + 2) + y + 1) * Wp + 1) * 256;
    const int tid = threadIdx.x;
    __shared__ bf16 L[16384];              // [x][c], chunk-swizzled by x&31
    const int cpd = 1024 >> lw;            // c rows per pass (float4 width)
    const int x4  = (tid & ((W >> 2) - 1)) << 2;
    const int cb4 = tid >> (lw - 2);
    const int passes = W >> 2;
    for (int p = 0; p < passes; ++p) {
        const int c = p * cpd + cb4;
        const float4 v = *(const float4*)(in + (size_t)c * H * W + x4);
#pragma unroll
        for (int j = 0; j < 4; ++j) {
            const int x = x4 + j;
            const float vj = (j == 0) ? v.x : (j == 1) ? v.y : (j == 2) ? v.z : v.w;
            L[x * 256 + ((((c >> 3) ^ (x & 31))) << 3) + (c & 7)] = (bf16)vj;
        }
    }
    __syncthreads();
    const int wpass = W >> 3;
    for (int q = 0; q < wpass; ++q) {
        const int id = q * 256 + tid;
        const int xo = id >> 5;
        const int k  = id & 31;
        bf16x8 vv = *(const bf16x8*)(L + xo * 256 + ((k ^ (xo & 31)) << 3));
        *(bf16x8*)(out + xo * 256 + k * 8) = vv;
    }
}

// zero borders of 5 contiguous padded buffers, all levels in one dispatch.
// R15: 8 border px per block (32 lanes x 8ch each), bf16x8 stores.
__global__ void border_zero_kernel(BZTab tb)
{
    const int bx = blockIdx.x;
    const int l  = (bx >= tb.xend0) + (bx >= tb.xend1);
    const int start = (l == 0) ? 0 : (l == 1 ? tb.xend0 : tb.xend1);
    const int i   = bx - start;
    const int buf = blockIdx.y;
    const int t   = threadIdx.x;
    const int H = tb.H[l];
    const int ppi = tb.ppi[l];
    const int pxid = i * 8 + (t >> 5);     // global border-px index
    const int ch8  = (t & 31) * 8;
    const int img = pxid / ppi;
    const int p   = pxid - img * ppi;
    const int Wp  = H + 2, Hp = H + 2;
    int y, xp;
    if (p < Wp)            { y = 0;      xp = p; }
    else if (p < 2 * Wp)   { y = Hp - 1; xp = p - Wp; }
    else { int q = p - 2 * Wp; y = 1 + (q >> 1); xp = (q & 1) ? (Wp - 1) : 0; }
    bf16x8 z = {};
    *(bf16x8*)(tb.base[l] + buf * tb.bufE[l] +
               ((size_t)(img * Hp + y) * Wp + xp) * 256 + ch8) = z;
}

// all weight prepacks in one dispatch:
//  [0,9216) stem cls, [9216,18432) stem box, [18432,19296) pred [t][96][256]
__global__ void prepack_kernel(const float* __restrict__ scw,
                               const float* __restrict__ sbw,
                               const float* __restrict__ pcw,
                               const float* __restrict__ pbw,
                               const float* __restrict__ prw,
                               const float* __restrict__ pcb,
                               const float* __restrict__ pbb,
                               const float* __restrict__ prb,
                               bf16* __restrict__ wc, bf16* __restrict__ wb,
                               bf16* __restrict__ pT, float* __restrict__ pB)
{
    const int ci = threadIdx.x;
    int g = blockIdx.x;
    if (g < 18432) {
        const float* w = (g < 9216) ? scw : sbw;
        bf16* o        = (g < 9216) ? wc  : wb;
        if (g >= 9216) g -= 9216;
        const int co = g & 255;
        const int st = g >> 8;
        const int s  = st / 9;
        const int t  = st - s * 9;
        o[(size_t)g * 256 + ci] = (bf16)w[(((s * 256 + co) * 256 + ci) * 9) + t];
    } else {
        g -= 18432;
        const int t  = g / 96;
        const int co = g - t * 96;
        float v = 0.0f;
        if (co < 80)       v = pcw[((co * 256 + ci) * 9) + t];
        else if (co < 84)  v = pbw[(((co - 80) * 256 + ci) * 9) + t];
        else if (co == 84) v = prw[(ci * 9) + t];
        pT[(size_t)g * 256 + ci] = (bf16)v;
        if (g == 0 && ci < 96) {
            float bvv = 0.0f;
            if (ci < 80)       bvv = pcb[ci];
            else if (ci < 84)  bvv = pbb[ci - 80];
            else if (ci == 84) bvv = prb[0];
            pB[ci] = bvv;
        }
    }
}

// ---------------------------------------------------------------------------
extern "C" void kernel_launch(void* const* d_in, const int* in_sizes, int n_in,
                              void* d_out, int out_size, void* d_ws, size_t ws_size,
                              hipStream_t stream)
{
    (void)in_sizes; (void)n_in; (void)out_size;
    const float* feat[3] = {(const float*)d_in[0], (const float*)d_in[1],
                            (const float*)d_in[2]};
    const float* scw = (const float*)d_in[3];
    const float* scb = (const float*)d_in[4];
    const float* sbw = (const float*)d_in[5];
    const float* sbb = (const float*)d_in[6];
    const float* pcw = (const float*)d_in[7];
    const float* pcb = (const float*)d_in[8];
    const float* pbw = (const float*)d_in[9];
    const float* pbb = (const float*)d_in[10];
    const float* prw = (const float*)d_in[11];
    const float* prb = (const float*)d_in[12];
    float* out = (float*)d_out;

    const int Hs[3]   = {64, 32, 16};
    const int lws[3]  = {6, 5, 4};
    const int lhws[3] = {12, 10, 8};
    const int offl[3] = {0, 4096, 5120};
    const int mtiles[3] = {512, 128, 32};          // M/128 per level
    size_t bufB[3];
    for (int l = 0; l < 3; ++l)
        bufB[l] = (size_t)16 * (Hs[l] + 2) * (Hs[l] + 2) * 256 * 2;

    const size_t WSTEM = (size_t)4 * 9 * 256 * 256 * 2;
    const size_t WPRED = (size_t)9 * 96 * 256 * 2;
    const size_t FULL   = 5 * (bufB[0] + bufB[1] + bufB[2]) + 2 * WSTEM + WPRED + 384;
    const size_t SHARED = 5 * bufB[0] + 2 * WSTEM + WPRED + 384;
    if (ws_size < SHARED) return;
    const bool fused = ws_size >= FULL;

    char* ws = (char*)d_ws;
    bf16* act[3][5];
    size_t off = 0;
    if (fused) {
        for (int l = 0; l < 3; ++l)
            for (int k = 0; k < 5; ++k) { act[l][k] = (bf16*)(ws + off); off += bufB[l]; }
    } else {
        for (int k = 0; k < 5; ++k)
            for (int l = 0; l < 3; ++l) act[l][k] = (bf16*)(ws + (size_t)k * bufB[0]);
        off = 5 * bufB[0];
    }
    bf16*  wbTc = (bf16*)(ws + off); off += WSTEM;
    bf16*  wbTb = (bf16*)(ws + off); off += WSTEM;
    bf16*  pT   = (bf16*)(ws + off); off += WPRED;
    float* pB   = (float*)(ws + off);

    prepack_kernel<<<dim3(19296), 256, 0, stream>>>(scw, sbw, pcw, pbw, prw,
                                                    pcb, pbb, prb,
                                                    wbTc, wbTb, pT, pB);

    auto make_stem_tab = [&](int s, int nlev, const int* levs) {
        StemTab tb{};
        for (int i = 0; i < nlev; ++i) {
            int l = levs[i];
            tb.inC[i]  = (s == 0) ? act[l][0] : ((s & 1) ? act[l][1] : act[l][2]);
            tb.inB[i]  = (s == 0) ? act[l][0] : ((s & 1) ? act[l][3] : act[l][4]);
            tb.outC[i] = (s & 1) ? act[l][2] : act[l][1];
            tb.outB[i] = (s & 1) ? act[l][4] : act[l][3];
            tb.H[i] = Hs[l]; tb.lw[i] = lws[l]; tb.lhw[i] = lhws[l];
        }
        return tb;
    };

    if (fused) {
        // border-zero: one dispatch, all levels x 5 bufs, 8 px/block
        BZTab bz{};
        int bpx[3];
        for (int l = 0; l < 3; ++l) {
            bz.base[l] = act[l][0]; bz.H[l] = Hs[l]; bz.bufE[l] = bufB[l] / 2;
            bpx[l] = 2 * (Hs[l] + 2) + 2 * Hs[l];
            bz.ppi[l] = bpx[l];
        }
        bz.xend0 = 2 * bpx[0]; bz.xend1 = bz.xend0 + 2 * bpx[1];
        const int bztot = bz.xend1 + 2 * bpx[2];
        border_zero_kernel<<<dim3(bztot, 5), 256, 0, stream>>>(bz);

        // cast: one dispatch, all levels
        CastTab ct{};
        for (int l = 0; l < 3; ++l) {
            ct.in[l] = feat[l]; ct.out[l] = act[l][0];
            ct.H[l] = Hs[l]; ct.lw[l] = lws[l];
        }
        ct.xend0 = 16 * Hs[0]; ct.xend1 = ct.xend0 + 16 * Hs[1];
        cast_pad_kernel<<<dim3(ct.xend1 + 16 * Hs[2]), 256, 0, stream>>>(ct);

        const int levs[3] = {0, 1, 2};
        const int tx0 = mtiles[0] * 2, tx1 = mtiles[1] * 2, tx2 = mtiles[2] * 2;
        for (int s = 0; s < 4; ++s) {
            StemTab tb = make_stem_tab(s, 3, levs);
            tb.xend0 = tx0; tb.xend1 = tx0 + tx1;
            stem_conv_kernel<<<dim3(tx0 + tx1 + tx2, 1, 2), 256, 0, stream>>>(
                tb, wbTc + (size_t)s * 589824, wbTb + (size_t)s * 589824,
                scb + s * 256, sbb + s * 256);
        }
        PredTab pt{};
        for (int l = 0; l < 3; ++l) {
            pt.inC[l] = act[l][2]; pt.inB[l] = act[l][4];
            pt.H[l] = Hs[l]; pt.lw[l] = lws[l]; pt.lhw[l] = lhws[l]; pt.offl[l] = offl[l];
        }
        pt.xend0 = mtiles[0]; pt.xend1 = mtiles[0] + mtiles[1];
        pred_conv_kernel<<<dim3(mtiles[0] + mtiles[1] + mtiles[2]), 256, 0, stream>>>(
            pt, pT, pB, out);
    } else {
        for (int l = 0; l < 3; ++l) {
            const int bpx = 2 * (Hs[l] + 2) + 2 * Hs[l];
            BZTab bz{};
            bz.base[0] = act[l][0]; bz.H[0] = Hs[l]; bz.bufE[0] = bufB[0] / 2;
            bz.ppi[0] = bpx; bz.xend0 = 2 * bpx; bz.xend1 = 2 * bpx;
            border_zero_kernel<<<dim3(2 * bpx, 5), 256, 0, stream>>>(bz);
            CastTab ct{};
            ct.in[0] = feat[l]; ct.out[0] = act[l][0];
            ct.H[0] = Hs[l]; ct.lw[0] = lws[l];
            ct.xend0 = 16 * Hs[l]; ct.xend1 = 16 * Hs[l];
            cast_pad_kernel<<<dim3(16 * Hs[l]), 256, 0, stream>>>(ct);

            const int levs[1] = {l};
            const int tiles = mtiles[l] * 2;
            for (int s = 0; s < 4; ++s) {
                StemTab tb = make_stem_tab(s, 1, levs);
                tb.xend0 = tiles; tb.xend1 = tiles;
                stem_conv_kernel<<<dim3(tiles, 1, 2), 256, 0, stream>>>(
                    tb, wbTc + (size_t)s * 589824, wbTb + (size_t)s * 589824,
                    scb + s * 256, sbb + s * 256);
            }
            PredTab pt{};
            pt.inC[0] = act[l][2]; pt.inB[0] = act[l][4];
            pt.H[0] = Hs[l]; pt.lw[0] = lws[l]; pt.lhw[0] = lhws[l]; pt.offl[0] = offl[l];
            pt.xend0 = mtiles[l]; pt.xend1 = mtiles[l];
            pred_conv_kernel<<<dim3(mtiles[l]), 256, 0, stream>>>(pt, pT, pB, out);
        }
    }
}